// Round 2
// baseline (787.639 us; speedup 1.0000x reference)
//
#include <hip/hip_runtime.h>

#define NNODES 100000
#define NEDGES 625000
#define DIM 128

// --- transpose W_l, W_r into WT[m][k][c] = W_m[c][k] (128 KB, L2-resident) ---
__global__ void transpose_w_kernel(const float* __restrict__ Wl,
                                   const float* __restrict__ Wr,
                                   float* __restrict__ WT) {
    int tid = blockIdx.x * blockDim.x + threadIdx.x;
    if (tid >= 2 * DIM * DIM) return;
    int m   = tid >> 14;            // which matrix
    int idx = tid & (DIM * DIM - 1);
    int k   = idx >> 7;
    int c   = idx & (DIM - 1);
    const float* W = m ? Wr : Wl;
    WT[tid] = W[c * DIM + k];       // write coalesced, read strided (tiny)
}

// --- scatter-add: one wave per edge; lane handles 2 floats ---
// NOTE: harness delivers ALL integer inputs as int32 (edge_index int64 in the
// reference arrives as int32 here). Reading as int64 was round-1's crash.
__global__ void scatter_kernel(const float* __restrict__ x,
                               const int* __restrict__ ei,
                               float* __restrict__ agg,
                               float* __restrict__ cnt) {
    int gtid = blockIdx.x * blockDim.x + threadIdx.x;
    int e    = gtid >> 6;
    int lane = threadIdx.x & 63;
    if (e >= NEDGES) return;
    int src = ei[e];            // wave-uniform broadcast load
    int dst = ei[NEDGES + e];
    float2 v = *(const float2*)(x + (size_t)src * DIM + 2 * lane);
    float* ad = agg + (size_t)dst * DIM + 2 * lane;
    unsafeAtomicAdd(ad, v.x);
    unsafeAtomicAdd(ad + 1, v.y);
    if (lane == 0) unsafeAtomicAdd(cnt + dst, 1.0f);
}

// --- fused mean-divide + dual GEMM + bias + relu ---
// block = 256 threads = 16 colgrp x 16 rowgrp; block tile = 64 rows x 128 cols
// thread tile = 4 rows x 8 cols. Reads agg from `out` in place, writes result.
// Each row's 16 reader/writer threads are 16 consecutive lanes of ONE wave
// (lockstep) -> all reads precede all writes -> no hazard.
__global__ __launch_bounds__(256) void transform_kernel(
    const float* __restrict__ x,
    const float* __restrict__ WT,    // [2][DIM][DIM], WT[m][k][c]
    const float* __restrict__ bias,
    const float* __restrict__ cnt,
    float* __restrict__ out)         // in: agg, out: result (in-place)
{
    const int colgrp = threadIdx.x & 15;
    const int rowgrp = threadIdx.x >> 4;
    const int c0 = colgrp * 8;
    const int r0 = blockIdx.x * 64 + rowgrp * 4;

    const float* WTl = WT;
    const float* WTr = WT + DIM * DIM;

    int   rows[4];
    float inv[4];
#pragma unroll
    for (int i = 0; i < 4; ++i) {
        int r = r0 + i;
        rows[i] = (r < NNODES) ? r : (NNODES - 1);   // clamped lanes never store
        inv[i]  = 1.0f / fmaxf(cnt[rows[i]], 1.0f);
    }

    float acc[4][8];
#pragma unroll
    for (int i = 0; i < 4; ++i)
#pragma unroll
        for (int j = 0; j < 8; ++j) acc[i][j] = 0.0f;

    for (int k4 = 0; k4 < DIM / 4; ++k4) {
        float4 am[4], ax[4];
#pragma unroll
        for (int i = 0; i < 4; ++i) {
            float4 a = *(const float4*)(out + (size_t)rows[i] * DIM + k4 * 4);
            am[i].x = a.x * inv[i]; am[i].y = a.y * inv[i];
            am[i].z = a.z * inv[i]; am[i].w = a.w * inv[i];
            ax[i] = *(const float4*)(x + (size_t)rows[i] * DIM + k4 * 4);
        }
#pragma unroll
        for (int kk = 0; kk < 4; ++kk) {
            int k = k4 * 4 + kk;
            float4 wl0 = *(const float4*)(WTl + k * DIM + c0);
            float4 wl1 = *(const float4*)(WTl + k * DIM + c0 + 4);
            float4 wr0 = *(const float4*)(WTr + k * DIM + c0);
            float4 wr1 = *(const float4*)(WTr + k * DIM + c0 + 4);
#pragma unroll
            for (int i = 0; i < 4; ++i) {
                float m  = (&am[i].x)[kk];
                float xv = (&ax[i].x)[kk];
                acc[i][0] += m * wl0.x + xv * wr0.x;
                acc[i][1] += m * wl0.y + xv * wr0.y;
                acc[i][2] += m * wl0.z + xv * wr0.z;
                acc[i][3] += m * wl0.w + xv * wr0.w;
                acc[i][4] += m * wl1.x + xv * wr1.x;
                acc[i][5] += m * wl1.y + xv * wr1.y;
                acc[i][6] += m * wl1.z + xv * wr1.z;
                acc[i][7] += m * wl1.w + xv * wr1.w;
            }
        }
    }

    float4 b0 = *(const float4*)(bias + c0);
    float4 b1 = *(const float4*)(bias + c0 + 4);
#pragma unroll
    for (int i = 0; i < 4; ++i) {
        int r = r0 + i;
        if (r < NNODES) {
            float4 o0, o1;
            o0.x = fmaxf(acc[i][0] + b0.x, 0.0f);
            o0.y = fmaxf(acc[i][1] + b0.y, 0.0f);
            o0.z = fmaxf(acc[i][2] + b0.z, 0.0f);
            o0.w = fmaxf(acc[i][3] + b0.w, 0.0f);
            o1.x = fmaxf(acc[i][4] + b1.x, 0.0f);
            o1.y = fmaxf(acc[i][5] + b1.y, 0.0f);
            o1.z = fmaxf(acc[i][6] + b1.z, 0.0f);
            o1.w = fmaxf(acc[i][7] + b1.w, 0.0f);
            *(float4*)(out + (size_t)r * DIM + c0)     = o0;
            *(float4*)(out + (size_t)r * DIM + c0 + 4) = o1;
        }
    }
}

extern "C" void kernel_launch(void* const* d_in, const int* in_sizes, int n_in,
                              void* d_out, int out_size, void* d_ws, size_t ws_size,
                              hipStream_t stream) {
    const float* x  = (const float*)d_in[0];
    const int*   ei = (const int*)d_in[1];   // int32! (harness converts int64)
    const float* Wl = (const float*)d_in[2];
    const float* Wr = (const float*)d_in[3];
    const float* b  = (const float*)d_in[4];
    float* out = (float*)d_out;

    // workspace layout: [0, 400KB) cnt ; [512KB, 640KB) WT
    float* cnt = (float*)d_ws;
    float* WT  = (float*)((char*)d_ws + (1 << 19));

    hipMemsetAsync(d_out, 0, (size_t)out_size * sizeof(float), stream);
    hipMemsetAsync(cnt, 0, NNODES * sizeof(float), stream);

    transpose_w_kernel<<<(2 * DIM * DIM + 255) / 256, 256, 0, stream>>>(Wl, Wr, WT);

    // one 64-lane wave per edge, 4 edges per 256-thread block
    long long total_threads = (long long)NEDGES * 64;
    int sblocks = (int)((total_threads + 255) / 256);
    scatter_kernel<<<sblocks, 256, 0, stream>>>(x, ei, out, cnt);

    transform_kernel<<<(NNODES + 63) / 64, 256, 0, stream>>>(x, WT, b, cnt, out);
}

// Round 3
// 560.092 us; speedup vs baseline: 1.4063x; 1.4063x over previous
//
#include <hip/hip_runtime.h>

#define NNODES 100000
#define NEDGES 625000
#define DIM 128
#define TM 64            // nodes per block in fused kernel
#define LDSPAD 132       // padded LDS row stride (floats): breaks 512B bank alias

// --- transpose W_l, W_r into WT[m][k][c] = W_m[c][k] (128 KB, L2-resident) ---
__global__ void transpose_w_kernel(const float* __restrict__ Wl,
                                   const float* __restrict__ Wr,
                                   float* __restrict__ WT) {
    int tid = blockIdx.x * blockDim.x + threadIdx.x;
    if (tid >= 2 * DIM * DIM) return;
    int m   = tid >> 14;
    int idx = tid & (DIM * DIM - 1);
    int k   = idx >> 7;
    int c   = idx & (DIM - 1);
    const float* W = m ? Wr : Wl;
    WT[tid] = W[c * DIM + k];
}

// --- CSR build step 1: degree histogram over destinations ---
__global__ void degree_kernel(const int* __restrict__ ei, int* __restrict__ deg) {
    int e = blockIdx.x * blockDim.x + threadIdx.x;
    if (e < NEDGES) atomicAdd(&deg[ei[NEDGES + e]], 1);
}

// --- CSR build step 2: single-block exclusive scan (100001 offsets) ---
__global__ __launch_bounds__(1024) void scan_kernel(const int* __restrict__ deg,
                                                    int* __restrict__ off) {
    __shared__ int part[1024];
    const int t  = threadIdx.x;
    const int CH = (NNODES + 1023) / 1024;   // 98
    const int base = t * CH;
    int s = 0;
    for (int i = 0; i < CH; ++i) {
        int idx = base + i;
        if (idx < NNODES) s += deg[idx];
    }
    part[t] = s;
    __syncthreads();
    // Hillis-Steele inclusive scan over 1024 partials
    for (int d = 1; d < 1024; d <<= 1) {
        int v = (t >= d) ? part[t - d] : 0;
        __syncthreads();
        part[t] += v;
        __syncthreads();
    }
    int run = part[t] - s;                   // exclusive prefix of this chunk
    for (int i = 0; i < CH; ++i) {
        int idx = base + i;
        if (idx < NNODES) { off[idx] = run; run += deg[idx]; }
    }
    if (t == 1023) off[NNODES] = run;        // == NEDGES
}

// --- CSR build step 3: fill adjacency; reuses deg as a countdown cursor ---
__global__ void fill_kernel(const int* __restrict__ ei, const int* __restrict__ off,
                            int* __restrict__ cursor, int* __restrict__ adj) {
    int e = blockIdx.x * blockDim.x + threadIdx.x;
    if (e >= NEDGES) return;
    int src = ei[e];
    int dst = ei[NEDGES + e];
    int old = atomicSub(&cursor[dst], 1);    // deg -> 0 after this pass
    adj[off[dst] + old - 1] = src;
}

// --- fused: CSR gather-mean (Phase A, -> LDS) + dual GEMM + bias + relu ---
// 256 threads = 4 waves; block owns TM=64 node rows.
// Phase A: wave w aggregates nodes w*16..w*16+15; lane holds 2 of 128 floats.
// Phase B: 16 colgrp x 16 rowgrp, thread tile 4 rows x 8 cols (as round 2).
__global__ __launch_bounds__(256) void fused_kernel(
    const float* __restrict__ x,
    const int*   __restrict__ off,
    const int*   __restrict__ adj,
    const float* __restrict__ WT,    // [2][DIM][DIM], WT[m][k][c]
    const float* __restrict__ bias,
    float* __restrict__ out)
{
    __shared__ float mean[TM][LDSPAD];
    const int lane = threadIdx.x & 63;
    const int wave = threadIdx.x >> 6;
    const int base = blockIdx.x * TM;

    // ---- Phase A: gather + mean into LDS ----
    for (int i = 0; i < 16; ++i) {
        int ln = wave * 16 + i;
        int n  = base + ln;
        if (n < NNODES) {
            int o0 = off[n], o1 = off[n + 1];       // wave-uniform scalar loads
            float ax = 0.0f, ay = 0.0f;
            for (int j = o0; j < o1; ++j) {
                int s = adj[j];                     // wave-uniform broadcast
                float2 v = *(const float2*)(x + (size_t)s * DIM + 2 * lane);
                ax += v.x; ay += v.y;
            }
            float inv = 1.0f / fmaxf((float)(o1 - o0), 1.0f);
            mean[ln][2 * lane]     = ax * inv;
            mean[ln][2 * lane + 1] = ay * inv;
        }
    }
    __syncthreads();

    // ---- Phase B: out = mean@Wl^T + x@Wr^T + b, relu ----
    const int colgrp = threadIdx.x & 15;
    const int rowgrp = threadIdx.x >> 4;
    const int c0  = colgrp * 8;
    const int lr0 = rowgrp * 4;

    const float* WTl = WT;
    const float* WTr = WT + DIM * DIM;

    int rows[4];
#pragma unroll
    for (int i = 0; i < 4; ++i) {
        int r = base + lr0 + i;
        rows[i] = (r < NNODES) ? r : (NNODES - 1);  // clamped lanes never store
    }

    float acc[4][8];
#pragma unroll
    for (int i = 0; i < 4; ++i)
#pragma unroll
        for (int j = 0; j < 8; ++j) acc[i][j] = 0.0f;

    for (int k4 = 0; k4 < DIM / 4; ++k4) {
        float4 am[4], axv[4];
#pragma unroll
        for (int i = 0; i < 4; ++i) {
            am[i]  = *(const float4*)(&mean[lr0 + i][k4 * 4]);
            axv[i] = *(const float4*)(x + (size_t)rows[i] * DIM + k4 * 4);
        }
#pragma unroll
        for (int kk = 0; kk < 4; ++kk) {
            int k = k4 * 4 + kk;
            float4 wl0 = *(const float4*)(WTl + k * DIM + c0);
            float4 wl1 = *(const float4*)(WTl + k * DIM + c0 + 4);
            float4 wr0 = *(const float4*)(WTr + k * DIM + c0);
            float4 wr1 = *(const float4*)(WTr + k * DIM + c0 + 4);
#pragma unroll
            for (int i = 0; i < 4; ++i) {
                float m  = (&am[i].x)[kk];
                float xv = (&axv[i].x)[kk];
                acc[i][0] += m * wl0.x + xv * wr0.x;
                acc[i][1] += m * wl0.y + xv * wr0.y;
                acc[i][2] += m * wl0.z + xv * wr0.z;
                acc[i][3] += m * wl0.w + xv * wr0.w;
                acc[i][4] += m * wl1.x + xv * wr1.x;
                acc[i][5] += m * wl1.y + xv * wr1.y;
                acc[i][6] += m * wl1.z + xv * wr1.z;
                acc[i][7] += m * wl1.w + xv * wr1.w;
            }
        }
    }

    float4 b0 = *(const float4*)(bias + c0);
    float4 b1 = *(const float4*)(bias + c0 + 4);
#pragma unroll
    for (int i = 0; i < 4; ++i) {
        int r = base + lr0 + i;
        if (r < NNODES) {
            float4 o0, o1;
            o0.x = fmaxf(acc[i][0] + b0.x, 0.0f);
            o0.y = fmaxf(acc[i][1] + b0.y, 0.0f);
            o0.z = fmaxf(acc[i][2] + b0.z, 0.0f);
            o0.w = fmaxf(acc[i][3] + b0.w, 0.0f);
            o1.x = fmaxf(acc[i][4] + b1.x, 0.0f);
            o1.y = fmaxf(acc[i][5] + b1.y, 0.0f);
            o1.z = fmaxf(acc[i][6] + b1.z, 0.0f);
            o1.w = fmaxf(acc[i][7] + b1.w, 0.0f);
            *(float4*)(out + (size_t)r * DIM + c0)     = o0;
            *(float4*)(out + (size_t)r * DIM + c0 + 4) = o1;
        }
    }
}

extern "C" void kernel_launch(void* const* d_in, const int* in_sizes, int n_in,
                              void* d_out, int out_size, void* d_ws, size_t ws_size,
                              hipStream_t stream) {
    const float* x  = (const float*)d_in[0];
    const int*   ei = (const int*)d_in[1];   // int32 (harness converts int64)
    const float* Wl = (const float*)d_in[2];
    const float* Wr = (const float*)d_in[3];
    const float* b  = (const float*)d_in[4];
    float* out = (float*)d_out;

    // workspace layout (needs ~4.2 MB):
    //   [0,       512K) off    int[NNODES+1]
    //   [512K,   1024K) deg    int[NNODES]   (doubles as fill cursor)
    //   [1M,      3.5M) adj    int[NEDGES]
    //   [4M,    4.125M) WT     float[2*DIM*DIM]
    int*   off = (int*)d_ws;
    int*   deg = (int*)((char*)d_ws + (512 << 10));
    int*   adj = (int*)((char*)d_ws + (1 << 20));
    float* WT  = (float*)((char*)d_ws + (4 << 20));

    hipMemsetAsync(deg, 0, NNODES * sizeof(int), stream);

    transpose_w_kernel<<<(2 * DIM * DIM + 255) / 256, 256, 0, stream>>>(Wl, Wr, WT);
    degree_kernel<<<(NEDGES + 255) / 256, 256, 0, stream>>>(ei, deg);
    scan_kernel<<<1, 1024, 0, stream>>>(deg, off);
    fill_kernel<<<(NEDGES + 255) / 256, 256, 0, stream>>>(ei, off, deg, adj);
    fused_kernel<<<(NNODES + TM - 1) / TM, 256, 0, stream>>>(x, off, adj, WT, b, out);
}

// Round 4
// 385.474 us; speedup vs baseline: 2.0433x; 1.4530x over previous
//
#include <hip/hip_runtime.h>

#define NNODES 100000
#define NEDGES 625000
#define DIM 128
#define TM 32            // nodes per block in fused kernel (100000 = 3125*32 exact)
#define LDSPAD 132       // padded LDS row stride (floats)
#define SCAN_B 1024
#define NSCAN ((NNODES + SCAN_B - 1) / SCAN_B)   // 98

// --- transpose W_l, W_r into WT[m][k][c] = W_m[c][k] (128 KB, L2-resident) ---
__global__ void transpose_w_kernel(const float* __restrict__ Wl,
                                   const float* __restrict__ Wr,
                                   float* __restrict__ WT) {
    int tid = blockIdx.x * blockDim.x + threadIdx.x;
    if (tid >= 2 * DIM * DIM) return;
    int m   = tid >> 14;
    int idx = tid & (DIM * DIM - 1);
    int k   = idx >> 7;
    int c   = idx & (DIM - 1);
    const float* W = m ? Wr : Wl;
    WT[tid] = W[c * DIM + k];
}

// --- CSR 1: degree histogram over destinations ---
__global__ void degree_kernel(const int* __restrict__ ei, int* __restrict__ deg) {
    int e = blockIdx.x * blockDim.x + threadIdx.x;
    if (e < NEDGES) atomicAdd(&deg[ei[NEDGES + e]], 1);
}

// --- CSR 2a: per-block sums (98 blocks x 1024) ---
__global__ __launch_bounds__(1024) void block_sum_kernel(const int* __restrict__ deg,
                                                         int* __restrict__ bsum) {
    __shared__ int red[SCAN_B];
    int gid = blockIdx.x * SCAN_B + threadIdx.x;
    red[threadIdx.x] = (gid < NNODES) ? deg[gid] : 0;
    __syncthreads();
    for (int s = SCAN_B / 2; s > 0; s >>= 1) {
        if (threadIdx.x < s) red[threadIdx.x] += red[threadIdx.x + s];
        __syncthreads();
    }
    if (threadIdx.x == 0) bsum[blockIdx.x] = red[0];
}

// --- CSR 2b: scan the 98 block sums (1 tiny block) ---
__global__ void scan_small_kernel(const int* __restrict__ bsum, int* __restrict__ boff) {
    __shared__ int v[128];
    int t = threadIdx.x;
    int orig = (t < NSCAN) ? bsum[t] : 0;
    v[t] = orig;
    __syncthreads();
    for (int d = 1; d < 128; d <<= 1) {
        int add = (t >= d) ? v[t - d] : 0;
        __syncthreads();
        v[t] += add;
        __syncthreads();
    }
    if (t < NSCAN) boff[t] = v[t] - orig;      // exclusive prefix
}

// --- CSR 2c: per-block exclusive scan + block offset -> off ---
__global__ __launch_bounds__(1024) void scan_block_kernel(const int* __restrict__ deg,
                                                          const int* __restrict__ boff,
                                                          int* __restrict__ off) {
    __shared__ int v[SCAN_B];
    int t = threadIdx.x;
    int gid = blockIdx.x * SCAN_B + t;
    int orig = (gid < NNODES) ? deg[gid] : 0;
    v[t] = orig;
    __syncthreads();
    for (int d = 1; d < SCAN_B; d <<= 1) {
        int add = (t >= d) ? v[t - d] : 0;
        __syncthreads();
        v[t] += add;
        __syncthreads();
    }
    if (gid < NNODES) off[gid] = boff[blockIdx.x] + v[t] - orig;
    if (gid == 0) off[NNODES] = NEDGES;        // total is a known constant
}

// --- CSR 3: fill adjacency; reuses deg as countdown cursor ---
__global__ void fill_kernel(const int* __restrict__ ei, const int* __restrict__ off,
                            int* __restrict__ cursor, int* __restrict__ adj) {
    int e = blockIdx.x * blockDim.x + threadIdx.x;
    if (e >= NEDGES) return;
    int src = ei[e];
    int dst = ei[NEDGES + e];
    int old = atomicSub(&cursor[dst], 1);
    adj[off[dst] + old - 1] = src;
}

// --- fused: CSR gather-mean (-> LDS) + dual GEMM + bias + relu ---
// 256 threads = 4 waves; block owns TM=32 rows (exact division, no tails).
// Phase A: wave handles 8 nodes; per step loads TWO neighbor rows (half-wave
// each, float4/lane) with 2x unroll -> 4 rows (2KB) in flight per wave.
// Phase B: 16 colgrp x 16 rowgrp, thread tile 2 rows x 8 cols.
__global__ __launch_bounds__(256) void fused_kernel(
    const float* __restrict__ x,
    const int*   __restrict__ off,
    const int*   __restrict__ adj,
    const float* __restrict__ WT,    // [2][DIM][DIM], WT[m][k][c]
    const float* __restrict__ bias,
    float* __restrict__ out)
{
    __shared__ float mean[TM][LDSPAD];
    const int lane = threadIdx.x & 63;
    const int wave = threadIdx.x >> 6;
    const int half = lane >> 5;       // which neighbor of the pair
    const int l32  = lane & 31;       // covers 128 floats as float4
    const int base = blockIdx.x * TM;

    // ---- Phase A ----
#pragma unroll
    for (int i = 0; i < 8; ++i) {
        const int ln = wave * 8 + i;
        const int n  = base + ln;
        const int o0 = off[n], o1 = off[n + 1];
        float4 a; a.x = a.y = a.z = a.w = 0.0f;
        int j = o0 + half;                       // halves take alternate nbrs
        for (; j + 2 < o1; j += 4) {             // 2 nbrs per half in flight
            int s0 = adj[j];
            int s1 = adj[j + 2];
            float4 v0 = *(const float4*)(x + (size_t)s0 * DIM + 4 * l32);
            float4 v1 = *(const float4*)(x + (size_t)s1 * DIM + 4 * l32);
            a.x += v0.x + v1.x; a.y += v0.y + v1.y;
            a.z += v0.z + v1.z; a.w += v0.w + v1.w;
        }
        if (j < o1) {
            int s0 = adj[j];
            float4 v0 = *(const float4*)(x + (size_t)s0 * DIM + 4 * l32);
            a.x += v0.x; a.y += v0.y; a.z += v0.z; a.w += v0.w;
        }
        // combine the two halves (lane l and l^32 hold the same 4 columns)
        float4 o;
        o.x = __shfl(a.x, lane ^ 32);
        o.y = __shfl(a.y, lane ^ 32);
        o.z = __shfl(a.z, lane ^ 32);
        o.w = __shfl(a.w, lane ^ 32);
        const float inv = 1.0f / fmaxf((float)(o1 - o0), 1.0f);
        if (half == 0) {
            float4 m4;
            m4.x = (a.x + o.x) * inv; m4.y = (a.y + o.y) * inv;
            m4.z = (a.z + o.z) * inv; m4.w = (a.w + o.w) * inv;
            *(float4*)(&mean[ln][4 * l32]) = m4;
        }
    }
    __syncthreads();

    // ---- Phase B: out = mean@Wl^T + x@Wr^T + b, relu ----
    const int colgrp = threadIdx.x & 15;
    const int rowgrp = threadIdx.x >> 4;
    const int c0  = colgrp * 8;
    const int lr0 = rowgrp * 2;
    const int r0  = base + lr0;

    const float* WTl = WT;
    const float* WTr = WT + DIM * DIM;

    float acc[2][8];
#pragma unroll
    for (int i = 0; i < 2; ++i)
#pragma unroll
        for (int j = 0; j < 8; ++j) acc[i][j] = 0.0f;

    for (int k4 = 0; k4 < DIM / 4; ++k4) {
        float4 am[2], axv[2];
#pragma unroll
        for (int i = 0; i < 2; ++i) {
            am[i]  = *(const float4*)(&mean[lr0 + i][k4 * 4]);
            axv[i] = *(const float4*)(x + (size_t)(r0 + i) * DIM + k4 * 4);
        }
#pragma unroll
        for (int kk = 0; kk < 4; ++kk) {
            int k = k4 * 4 + kk;
            float4 wl0 = *(const float4*)(WTl + k * DIM + c0);
            float4 wl1 = *(const float4*)(WTl + k * DIM + c0 + 4);
            float4 wr0 = *(const float4*)(WTr + k * DIM + c0);
            float4 wr1 = *(const float4*)(WTr + k * DIM + c0 + 4);
#pragma unroll
            for (int i = 0; i < 2; ++i) {
                float m  = (&am[i].x)[kk];
                float xv = (&axv[i].x)[kk];
                acc[i][0] += m * wl0.x + xv * wr0.x;
                acc[i][1] += m * wl0.y + xv * wr0.y;
                acc[i][2] += m * wl0.z + xv * wr0.z;
                acc[i][3] += m * wl0.w + xv * wr0.w;
                acc[i][4] += m * wl1.x + xv * wr1.x;
                acc[i][5] += m * wl1.y + xv * wr1.y;
                acc[i][6] += m * wl1.z + xv * wr1.z;
                acc[i][7] += m * wl1.w + xv * wr1.w;
            }
        }
    }

    float4 b0 = *(const float4*)(bias + c0);
    float4 b1 = *(const float4*)(bias + c0 + 4);
#pragma unroll
    for (int i = 0; i < 2; ++i) {
        float4 o0v, o1v;
        o0v.x = fmaxf(acc[i][0] + b0.x, 0.0f);
        o0v.y = fmaxf(acc[i][1] + b0.y, 0.0f);
        o0v.z = fmaxf(acc[i][2] + b0.z, 0.0f);
        o0v.w = fmaxf(acc[i][3] + b0.w, 0.0f);
        o1v.x = fmaxf(acc[i][4] + b1.x, 0.0f);
        o1v.y = fmaxf(acc[i][5] + b1.y, 0.0f);
        o1v.z = fmaxf(acc[i][6] + b1.z, 0.0f);
        o1v.w = fmaxf(acc[i][7] + b1.w, 0.0f);
        *(float4*)(out + (size_t)(r0 + i) * DIM + c0)     = o0v;
        *(float4*)(out + (size_t)(r0 + i) * DIM + c0 + 4) = o1v;
    }
}

extern "C" void kernel_launch(void* const* d_in, const int* in_sizes, int n_in,
                              void* d_out, int out_size, void* d_ws, size_t ws_size,
                              hipStream_t stream) {
    const float* x  = (const float*)d_in[0];
    const int*   ei = (const int*)d_in[1];   // int32 (harness converts int64)
    const float* Wl = (const float*)d_in[2];
    const float* Wr = (const float*)d_in[3];
    const float* b  = (const float*)d_in[4];
    float* out = (float*)d_out;

    // workspace layout (~4.2 MB):
    //   [0,     512K) off   int[NNODES+1]
    //   [512K, 1024K) deg   int[NNODES] (doubles as fill cursor)
    //   [1M,    3.5M) adj   int[NEDGES]
    //   [3.5M,  +4K ) bsum  int[NSCAN]
    //   [3.5M+4K,+4K) boff  int[NSCAN]
    //   [4M,  4.125M) WT    float[2*DIM*DIM]
    int*   off  = (int*)d_ws;
    int*   deg  = (int*)((char*)d_ws + (512 << 10));
    int*   adj  = (int*)((char*)d_ws + (1 << 20));
    int*   bsum = (int*)((char*)d_ws + 3584 * 1024);
    int*   boff = (int*)((char*)d_ws + 3588 * 1024);
    float* WT   = (float*)((char*)d_ws + (4 << 20));

    hipMemsetAsync(deg, 0, NNODES * sizeof(int), stream);

    transpose_w_kernel<<<(2 * DIM * DIM + 255) / 256, 256, 0, stream>>>(Wl, Wr, WT);
    degree_kernel<<<(NEDGES + 255) / 256, 256, 0, stream>>>(ei, deg);
    block_sum_kernel<<<NSCAN, SCAN_B, 0, stream>>>(deg, bsum);
    scan_small_kernel<<<1, 128, 0, stream>>>(bsum, boff);
    scan_block_kernel<<<NSCAN, SCAN_B, 0, stream>>>(deg, boff, off);
    fill_kernel<<<(NEDGES + 255) / 256, 256, 0, stream>>>(ei, off, deg, adj);
    fused_kernel<<<NNODES / TM, 256, 0, stream>>>(x, off, adj, WT, b, out);
}